// Round 1
// baseline (8070.068 us; speedup 1.0000x reference)
//
#include <hip/hip_runtime.h>
#include <math.h>

// Problem constants (match reference)
#define BB 256
#define NOBJ 100
#define NKEEP 36
#define DD 2048
#define HID 1024
#define KS 256
#define H2 512
#define NP1 (NKEEP + 1)
#define N4H 2048   // 4*H2
#define GB 4       // batches per block in step kernels

__device__ __forceinline__ float sigf(float x) { return 1.0f / (1.0f + expf(-x)); }

// ---------------------------------------------------------------------------
// K1: per-batch top-NKEEP by attention (stable, descending), gather boxes,
// init parent sentinel.
__global__ __launch_bounds__(128) void topk_kernel(
    const float* __restrict__ att, const float* __restrict__ boxes,
    int* __restrict__ idx, float* __restrict__ att_sig,
    float* __restrict__ bxk, int* __restrict__ parent) {
  int b = blockIdx.x;
  int t = threadIdx.x;
  __shared__ float a[NOBJ];
  if (t < NOBJ) a[t] = att[b * NOBJ + t];
  __syncthreads();
  if (t < NOBJ) {
    float ai = a[t];
    int rank = 0;
    for (int j = 0; j < NOBJ; j++) {
      float aj = a[j];
      rank += (aj > ai) || (aj == ai && j < t);
    }
    if (rank < NKEEP) {
      idx[b * NKEEP + rank] = t;
      att_sig[b * NKEEP + rank] = 1.0f / (1.0f + expf(-ai));
      for (int c = 0; c < 4; c++)
        bxk[(b * NKEEP + rank) * 4 + c] = boxes[(b * 4 + c) * NOBJ + t];
    }
  }
  if (t < NKEEP) parent[b * NKEEP + t] = NKEEP;  // sentinel
}

// ---------------------------------------------------------------------------
// K2: gather x[b][n][d] = vf[b][d][idx[b][n]] via LDS transpose tile.
__global__ __launch_bounds__(256) void gather_x(
    const float* __restrict__ vf, const int* __restrict__ idx,
    float* __restrict__ x) {
  int b = blockIdx.x;
  int d0 = blockIdx.y * 32;
  __shared__ float s[32][101];  // pad 101: stride-5 bank walk, conflict-free
  __shared__ int idxs[NKEEP];
  int tid = threadIdx.x;
  if (tid < NKEEP) idxs[tid] = idx[b * NKEEP + tid];
  for (int l = tid; l < 32 * NOBJ; l += 256) {
    int dd = l / NOBJ, c = l % NOBJ;
    s[dd][c] = vf[((size_t)b * DD + d0 + dd) * NOBJ + c];
  }
  __syncthreads();
  for (int l = tid; l < 32 * NKEEP; l += 256) {
    int dd = l % 32, n = l / 32;
    x[((size_t)b * NKEEP + n) * DD + d0 + dd] = s[dd][idxs[n]];
  }
}

// ---------------------------------------------------------------------------
// K3: f[b][n][k] = tanh(sum_d vo[b,d,idx[n]]*Wv[d,k] + sum_c bx[b,n,c]*Wb[c,k])
// One block per batch; thread = k column; acc over all 36 n in registers.
__global__ __launch_bounds__(256) void f_kernel(
    const float* __restrict__ vo, const float* __restrict__ Wv,
    const float* __restrict__ Wb, const int* __restrict__ idx,
    const float* __restrict__ bxk, float* __restrict__ fmat) {
  int b = blockIdx.x;
  int k = threadIdx.x;  // 0..255
  __shared__ int idxs[NKEEP];
  __shared__ float vs[16][NKEEP];
  if (k < NKEEP) idxs[k] = idx[b * NKEEP + k];
  __syncthreads();
  float acc[NKEEP];
#pragma unroll
  for (int n = 0; n < NKEEP; n++) acc[n] = 0.0f;
  for (int d0 = 0; d0 < DD; d0 += 16) {
    __syncthreads();
    for (int l = k; l < 16 * NKEEP; l += 256) {
      int dd = l / NKEEP, n = l % NKEEP;
      vs[dd][n] = vo[((size_t)b * DD + d0 + dd) * NOBJ + idxs[n]];
    }
    __syncthreads();
#pragma unroll
    for (int dd = 0; dd < 16; dd++) {
      float w = Wv[(size_t)(d0 + dd) * KS + k];
#pragma unroll
      for (int n = 0; n < NKEEP; n++) acc[n] += vs[dd][n] * w;
    }
  }
  for (int n = 0; n < NKEEP; n++) {
    float s = acc[n];
#pragma unroll
    for (int c = 0; c < 4; c++) s += bxk[(b * NKEEP + n) * 4 + c] * Wb[c * KS + k];
    fmat[((size_t)b * NKEEP + n) * KS + k] = tanhf(s);
  }
}

// ---------------------------------------------------------------------------
// K4: S[b][i][j] = sigmoid((f_i . f_j)/16) * att_i * att_j   (f64 accum dot)
__global__ __launch_bounds__(256) void s_kernel(
    const float* __restrict__ fmat, const float* __restrict__ att_sig,
    float* __restrict__ S) {
  int b = blockIdx.x;
  int tid = threadIdx.x;
  __shared__ float fs[NKEEP][KS + 1];
  __shared__ float as[NKEEP];
  for (int l = tid; l < NKEEP * KS; l += 256) {
    int n = l / KS, k = l % KS;
    fs[n][k] = fmat[((size_t)b * NKEEP + n) * KS + k];
  }
  if (tid < NKEEP) as[tid] = att_sig[b * NKEEP + tid];
  __syncthreads();
  for (int p = tid; p < NKEEP * NKEEP; p += 256) {
    int i = p / NKEEP, j = p % NKEEP;
    double acc = 0.0;
    for (int k = 0; k < KS; k++) acc += (double)fs[i][k] * (double)fs[j][k];
    float sc = 1.0f / (1.0f + expf(-(float)(acc * (1.0 / 16.0))));
    S[((size_t)b * NKEEP + i) * NKEEP + j] = sc * as[i] * as[j];
  }
}

// ---------------------------------------------------------------------------
// K5: Prim MST forest, one wave per batch. argmax ties -> smallest flat index
// (matches jnp.argmax on the flattened [N,N] candidate matrix).
__global__ __launch_bounds__(64) void prim_kernel(
    const float* __restrict__ S, int* __restrict__ parent,
    int* __restrict__ order) {
  int b = blockIdx.x;
  int lane = threadIdx.x;  // 0..63, single wave
  __shared__ float Ss[NKEEP * NKEEP];
  for (int l = lane; l < NKEEP * NKEEP; l += 64) Ss[l] = S[(size_t)b * NKEEP * NKEEP + l];
  __syncthreads();
  unsigned long long mask = 1ull;  // root = 0 (att_top sorted desc -> argmax=0)
  if (lane == 0) order[b * NKEEP + 0] = 0;
  for (int step = 1; step < NKEEP; step++) {
    float bv = -1.0f;
    int bk = NKEEP * NKEEP;
    for (int l = lane; l < NKEEP * NKEEP; l += 64) {
      int p = l / NKEEP, c = l % NKEEP;
      if (((mask >> p) & 1ull) && !((mask >> c) & 1ull)) {
        float v = Ss[l];
        if (v > bv || (v == bv && l < bk)) { bv = v; bk = l; }
      }
    }
    for (int off = 32; off > 0; off >>= 1) {
      float ov = __shfl_down(bv, off);
      int ok = __shfl_down(bk, off);
      if (ov > bv || (ov == bv && ok < bk)) { bv = ov; bk = ok; }
    }
    bk = __shfl(bk, 0);
    int p = bk / NKEEP, c = bk % NKEEP;
    mask |= (1ull << c);
    if (lane == 0) {
      parent[b * NKEEP + c] = p;
      order[b * NKEEP + step] = c;
    }
  }
}

// ---------------------------------------------------------------------------
// K6: f32 tiled GEMM  C[9216,2048] = A[9216,2048] @ W[2048,2048] + bias
// 64x64 tile, 4x4 per thread, Ktile=16, n-group-of-8 block swizzle for L2.
__global__ __launch_bounds__(256) void gemm_kernel(
    const float* __restrict__ A, const float* __restrict__ W,
    const float* __restrict__ bias, float* __restrict__ C) {
  __shared__ float As[16][68];  // [k][m], padded (272B rows, 16B aligned)
  __shared__ float Bs[16][68];  // [k][n]
  const int MT = (BB * NKEEP) / 64;  // 144
  const int GRP = 8;
  int bid = blockIdx.x;
  int g = bid / (MT * GRP);
  int r = bid % (MT * GRP);
  int mt = r / GRP;
  int nt = g * GRP + (r % GRP);
  int m0 = mt * 64, n0 = nt * 64;
  int tid = threadIdx.x;
  int tx = tid & 15, ty = tid >> 4;
  float acc[4][4];
#pragma unroll
  for (int i = 0; i < 4; i++)
#pragma unroll
    for (int j = 0; j < 4; j++) acc[i][j] = 0.0f;
  int la_i = tid >> 2;
  int la_k = (tid & 3) * 4;
  int lb_k = tid >> 4;
  int lb_j = (tid & 15) * 4;
  for (int k0 = 0; k0 < DD; k0 += 16) {
    __syncthreads();
    float4 av = *(const float4*)&A[(size_t)(m0 + la_i) * DD + k0 + la_k];
    As[la_k + 0][la_i] = av.x;
    As[la_k + 1][la_i] = av.y;
    As[la_k + 2][la_i] = av.z;
    As[la_k + 3][la_i] = av.w;
    *(float4*)&Bs[lb_k][lb_j] = *(const float4*)&W[(size_t)(k0 + lb_k) * N4H + n0 + lb_j];
    __syncthreads();
#pragma unroll
    for (int kk = 0; kk < 16; kk++) {
      float4 a = *(const float4*)&As[kk][ty * 4];
      float4 bv = *(const float4*)&Bs[kk][tx * 4];
      acc[0][0] += a.x * bv.x; acc[0][1] += a.x * bv.y; acc[0][2] += a.x * bv.z; acc[0][3] += a.x * bv.w;
      acc[1][0] += a.y * bv.x; acc[1][1] += a.y * bv.y; acc[1][2] += a.y * bv.z; acc[1][3] += a.y * bv.w;
      acc[2][0] += a.z * bv.x; acc[2][1] += a.z * bv.y; acc[2][2] += a.z * bv.z; acc[2][3] += a.z * bv.w;
      acc[3][0] += a.w * bv.x; acc[3][1] += a.w * bv.y; acc[3][2] += a.w * bv.z; acc[3][3] += a.w * bv.w;
    }
  }
  float4 bv = *(const float4*)&bias[n0 + tx * 4];
#pragma unroll
  for (int i = 0; i < 4; i++) {
    int row = m0 + ty * 4 + i;
    float4 o;
    o.x = acc[i][0] + bv.x;
    o.y = acc[i][1] + bv.y;
    o.z = acc[i][2] + bv.z;
    o.w = acc[i][3] + bv.w;
    *(float4*)&C[(size_t)row * N4H + n0 + tx * 4] = o;
  }
}

// ---------------------------------------------------------------------------
// K7: one bottom-up TreeLSTM step (t). grid (BB/GB, 2); thread k = by*256+tid.
__global__ __launch_bounds__(256) void up_step_kernel(
    int t, const float* __restrict__ xW, const float* __restrict__ Wh,
    const int* __restrict__ order, const int* __restrict__ parent,
    float* __restrict__ hsum, float* __restrict__ csum,
    float* __restrict__ hup) {
  int bg = blockIdx.x;
  int k = blockIdx.y * 256 + threadIdx.x;  // 0..511
  int tid = threadIdx.x;
  __shared__ float hs[GB][H2];
  __shared__ int nodes[GB], pars[GB];
  if (tid < GB) {
    int b = bg * GB + tid;
    int nd = order[b * NKEEP + t];
    nodes[tid] = nd;
    pars[tid] = parent[b * NKEEP + nd];
  }
  __syncthreads();
  for (int g = 0; g < GB; g++) {
    int b = bg * GB + g;
    for (int j = tid; j < H2; j += 256)
      hs[g][j] = hsum[((size_t)b * NP1 + nodes[g]) * H2 + j];
  }
  __syncthreads();
  float ai[GB], af[GB], ag[GB], ao[GB];
#pragma unroll
  for (int g = 0; g < GB; g++) { ai[g] = af[g] = ag[g] = ao[g] = 0.0f; }
  for (int j = 0; j < H2; j++) {
    const float* wr = &Wh[(size_t)j * N4H];
    float wi = wr[k], wf = wr[H2 + k], wg = wr[2 * H2 + k], wo = wr[3 * H2 + k];
#pragma unroll
    for (int g = 0; g < GB; g++) {
      float h = hs[g][j];
      ai[g] += h * wi; af[g] += h * wf; ag[g] += h * wg; ao[g] += h * wo;
    }
  }
#pragma unroll
  for (int g = 0; g < GB; g++) {
    int b = bg * GB + g;
    int nd = nodes[g], pr = pars[g];
    const float* xw = &xW[((size_t)b * NKEEP + nd) * N4H];
    float pi = xw[k] + ai[g];
    float pf = xw[H2 + k] + af[g];
    float pg = xw[2 * H2 + k] + ag[g];
    float po = xw[3 * H2 + k] + ao[g];
    float cprev = csum[((size_t)b * NP1 + nd) * H2 + k];
    float c = sigf(pi) * tanhf(pg) + sigf(pf) * cprev;
    float h = sigf(po) * tanhf(c);
    hup[((size_t)b * NKEEP + nd) * H2 + k] = h;
    hsum[((size_t)b * NP1 + pr) * H2 + k] += h;
    csum[((size_t)b * NP1 + pr) * H2 + k] += c;
  }
}

// ---------------------------------------------------------------------------
// K8: one top-down TreeLSTM step (t).
__global__ __launch_bounds__(256) void dn_step_kernel(
    int t, const float* __restrict__ xW, const float* __restrict__ Wh,
    const int* __restrict__ order, const int* __restrict__ parent,
    float* __restrict__ hd, float* __restrict__ cd) {
  int bg = blockIdx.x;
  int k = blockIdx.y * 256 + threadIdx.x;
  int tid = threadIdx.x;
  __shared__ float hs[GB][H2];
  __shared__ int nodes[GB], pars[GB];
  if (tid < GB) {
    int b = bg * GB + tid;
    int nd = order[b * NKEEP + t];
    nodes[tid] = nd;
    pars[tid] = parent[b * NKEEP + nd];
  }
  __syncthreads();
  for (int g = 0; g < GB; g++) {
    int b = bg * GB + g;
    for (int j = tid; j < H2; j += 256)
      hs[g][j] = hd[((size_t)b * NP1 + pars[g]) * H2 + j];
  }
  __syncthreads();
  float ai[GB], af[GB], ag[GB], ao[GB];
#pragma unroll
  for (int g = 0; g < GB; g++) { ai[g] = af[g] = ag[g] = ao[g] = 0.0f; }
  for (int j = 0; j < H2; j++) {
    const float* wr = &Wh[(size_t)j * N4H];
    float wi = wr[k], wf = wr[H2 + k], wg = wr[2 * H2 + k], wo = wr[3 * H2 + k];
#pragma unroll
    for (int g = 0; g < GB; g++) {
      float h = hs[g][j];
      ai[g] += h * wi; af[g] += h * wf; ag[g] += h * wg; ao[g] += h * wo;
    }
  }
#pragma unroll
  for (int g = 0; g < GB; g++) {
    int b = bg * GB + g;
    int nd = nodes[g], pr = pars[g];
    const float* xw = &xW[((size_t)b * NKEEP + nd) * N4H];
    float pi = xw[k] + ai[g];
    float pf = xw[H2 + k] + af[g];
    float pg = xw[2 * H2 + k] + ag[g];
    float po = xw[3 * H2 + k] + ao[g];
    float cprev = cd[((size_t)b * NP1 + pr) * H2 + k];
    float c = sigf(pi) * tanhf(pg) + sigf(pf) * cprev;
    float h = sigf(po) * tanhf(c);
    hd[((size_t)b * NP1 + nd) * H2 + k] = h;
    cd[((size_t)b * NP1 + nd) * H2 + k] = c;
  }
}

// ---------------------------------------------------------------------------
// K9: out[b][q][n] = q<512 ? hup[b][n][q] : hd[b][n][q-512]  (LDS transpose)
__global__ __launch_bounds__(256) void out_transpose(
    const float* __restrict__ hup, const float* __restrict__ hd,
    float* __restrict__ out) {
  int b = blockIdx.x;
  __shared__ float s[NKEEP][65];
  for (int half = 0; half < 2; half++) {
    const float* src = half ? hd : hup;
    int rs = half ? NP1 : NKEEP;
    for (int q0 = 0; q0 < H2; q0 += 64) {
      __syncthreads();
      for (int l = threadIdx.x; l < NKEEP * 64; l += 256) {
        int n = l / 64, qq = l % 64;
        s[n][qq] = src[((size_t)b * rs + n) * H2 + q0 + qq];
      }
      __syncthreads();
      for (int l = threadIdx.x; l < NKEEP * 64; l += 256) {
        int qq = l / NKEEP, n = l % NKEEP;
        out[(size_t)b * (HID * NKEEP) + (half * H2 + q0 + qq) * NKEEP + n] = s[n][qq];
      }
    }
  }
}

// ---------------------------------------------------------------------------
extern "C" void kernel_launch(void* const* d_in, const int* in_sizes, int n_in,
                              void* d_out, int out_size, void* d_ws, size_t ws_size,
                              hipStream_t stream) {
  const float* boxes = (const float*)d_in[0];
  const float* attention = (const float*)d_in[1];
  const float* vf = (const float*)d_in[2];
  const float* vo = (const float*)d_in[3];
  // d_in[4] que_type: unused by the forward
  const float* Wv = (const float*)d_in[5];
  const float* Wb = (const float*)d_in[6];
  const float* Wx_up = (const float*)d_in[7];
  const float* Wh_up = (const float*)d_in[8];
  const float* b_up = (const float*)d_in[9];
  const float* Wx_dn = (const float*)d_in[10];
  const float* Wh_dn = (const float*)d_in[11];
  const float* b_dn = (const float*)d_in[12];
  float* out = (float*)d_out;

  char* ws = (char*)d_ws;
  size_t off = 0;
  auto take = [&](size_t bytes) -> char* {
    char* p = ws + off;
    off = (off + bytes + 255) & ~(size_t)255;
    return p;
  };
  int* idx = (int*)take((size_t)BB * NKEEP * 4);
  float* att_sig = (float*)take((size_t)BB * NKEEP * 4);
  float* bxk = (float*)take((size_t)BB * NKEEP * 4 * 4);
  int* parent = (int*)take((size_t)BB * NKEEP * 4);
  int* order = (int*)take((size_t)BB * NKEEP * 4);
  float* fmat = (float*)take((size_t)BB * NKEEP * KS * 4);
  float* S = (float*)take((size_t)BB * NKEEP * NKEEP * 4);
  float* x = (float*)take((size_t)BB * NKEEP * DD * 4);
  float* xWu = (float*)take((size_t)BB * NKEEP * N4H * 4);
  float* xWd = (float*)take((size_t)BB * NKEEP * N4H * 4);
  float* hsum = (float*)take((size_t)BB * NP1 * H2 * 4);
  float* csum = (float*)take((size_t)BB * NP1 * H2 * 4);
  float* hd = (float*)take((size_t)BB * NP1 * H2 * 4);
  float* cd = (float*)take((size_t)BB * NP1 * H2 * 4);
  float* hup = x;  // alias: x is dead after the two big GEMMs

  topk_kernel<<<BB, 128, 0, stream>>>(attention, boxes, idx, att_sig, bxk, parent);
  gather_x<<<dim3(BB, DD / 32), 256, 0, stream>>>(vf, idx, x);
  f_kernel<<<BB, 256, 0, stream>>>(vo, Wv, Wb, idx, bxk, fmat);
  s_kernel<<<BB, 256, 0, stream>>>(fmat, att_sig, S);
  prim_kernel<<<BB, 64, 0, stream>>>(S, parent, order);

  int gblocks = ((BB * NKEEP) / 64) * (N4H / 64);  // 144*32 = 4608
  gemm_kernel<<<gblocks, 256, 0, stream>>>(x, Wx_up, b_up, xWu);
  gemm_kernel<<<gblocks, 256, 0, stream>>>(x, Wx_dn, b_dn, xWd);

  size_t accb = (size_t)BB * NP1 * H2 * 4;
  hipMemsetAsync(hsum, 0, accb, stream);
  hipMemsetAsync(csum, 0, accb, stream);
  hipMemsetAsync(hd, 0, accb, stream);
  hipMemsetAsync(cd, 0, accb, stream);

  for (int t = NKEEP - 1; t >= 0; --t)
    up_step_kernel<<<dim3(BB / GB, 2), 256, 0, stream>>>(t, xWu, Wh_up, order, parent, hsum, csum, hup);
  for (int t = 0; t < NKEEP; ++t)
    dn_step_kernel<<<dim3(BB / GB, 2), 256, 0, stream>>>(t, xWd, Wh_dn, order, parent, hd, cd);

  out_transpose<<<BB, 256, 0, stream>>>(hup, hd, out);
}

// Round 2
// 4770.882 us; speedup vs baseline: 1.6915x; 1.6915x over previous
//
#include <hip/hip_runtime.h>
#include <math.h>

// Problem constants (match reference)
#define BB 256
#define NOBJ 100
#define NKEEP 36
#define DD 2048
#define HID 1024
#define KS 256
#define H2 512
#define NP1 (NKEEP + 1)
#define N4H 2048   // 4*H2
#define SBGB 8     // batches per block in step kernels
#define SKR 64     // k-columns per block in step kernels

__device__ __forceinline__ float sigf(float x) { return 1.0f / (1.0f + expf(-x)); }

// ---------------------------------------------------------------------------
// K1: per-batch top-NKEEP by attention (stable, descending), gather boxes,
// init parent sentinel.
__global__ __launch_bounds__(128) void topk_kernel(
    const float* __restrict__ att, const float* __restrict__ boxes,
    int* __restrict__ idx, float* __restrict__ att_sig,
    float* __restrict__ bxk, int* __restrict__ parent) {
  int b = blockIdx.x;
  int t = threadIdx.x;
  __shared__ float a[NOBJ];
  if (t < NOBJ) a[t] = att[b * NOBJ + t];
  __syncthreads();
  if (t < NOBJ) {
    float ai = a[t];
    int rank = 0;
    for (int j = 0; j < NOBJ; j++) {
      float aj = a[j];
      rank += (aj > ai) || (aj == ai && j < t);
    }
    if (rank < NKEEP) {
      idx[b * NKEEP + rank] = t;
      att_sig[b * NKEEP + rank] = 1.0f / (1.0f + expf(-ai));
      for (int c = 0; c < 4; c++)
        bxk[(b * NKEEP + rank) * 4 + c] = boxes[(b * 4 + c) * NOBJ + t];
    }
  }
  if (t < NKEEP) parent[b * NKEEP + t] = NKEEP;  // sentinel
}

// ---------------------------------------------------------------------------
// K2: gather x[b][n][d] = vf[b][d][idx[b][n]] via LDS transpose tile.
__global__ __launch_bounds__(256) void gather_x(
    const float* __restrict__ vf, const int* __restrict__ idx,
    float* __restrict__ x) {
  int b = blockIdx.x;
  int d0 = blockIdx.y * 32;
  __shared__ float s[32][101];
  __shared__ int idxs[NKEEP];
  int tid = threadIdx.x;
  if (tid < NKEEP) idxs[tid] = idx[b * NKEEP + tid];
  for (int l = tid; l < 32 * NOBJ; l += 256) {
    int dd = l / NOBJ, c = l % NOBJ;
    s[dd][c] = vf[((size_t)b * DD + d0 + dd) * NOBJ + c];
  }
  __syncthreads();
  for (int l = tid; l < 32 * NKEEP; l += 256) {
    int dd = l % 32, n = l / 32;
    x[((size_t)b * NKEEP + n) * DD + d0 + dd] = s[dd][idxs[n]];
  }
}

// ---------------------------------------------------------------------------
// K3: f[b][n][k] = tanh(sum_d vo[b,d,idx[n]]*Wv[d,k] + sum_c bx[b,n,c]*Wb[c,k])
__global__ __launch_bounds__(256) void f_kernel(
    const float* __restrict__ vo, const float* __restrict__ Wv,
    const float* __restrict__ Wb, const int* __restrict__ idx,
    const float* __restrict__ bxk, float* __restrict__ fmat) {
  int b = blockIdx.x;
  int k = threadIdx.x;  // 0..255
  __shared__ int idxs[NKEEP];
  __shared__ float vs[16][NKEEP];
  if (k < NKEEP) idxs[k] = idx[b * NKEEP + k];
  __syncthreads();
  float acc[NKEEP];
#pragma unroll
  for (int n = 0; n < NKEEP; n++) acc[n] = 0.0f;
  for (int d0 = 0; d0 < DD; d0 += 16) {
    __syncthreads();
    for (int l = k; l < 16 * NKEEP; l += 256) {
      int dd = l / NKEEP, n = l % NKEEP;
      vs[dd][n] = vo[((size_t)b * DD + d0 + dd) * NOBJ + idxs[n]];
    }
    __syncthreads();
#pragma unroll
    for (int dd = 0; dd < 16; dd++) {
      float w = Wv[(size_t)(d0 + dd) * KS + k];
#pragma unroll
      for (int n = 0; n < NKEEP; n++) acc[n] += vs[dd][n] * w;
    }
  }
  for (int n = 0; n < NKEEP; n++) {
    float s = acc[n];
#pragma unroll
    for (int c = 0; c < 4; c++) s += bxk[(b * NKEEP + n) * 4 + c] * Wb[c * KS + k];
    fmat[((size_t)b * NKEEP + n) * KS + k] = tanhf(s);
  }
}

// ---------------------------------------------------------------------------
// K4: S[b][i][j] = sigmoid((f_i . f_j)/16) * att_i * att_j   (f64 accum dot)
__global__ __launch_bounds__(256) void s_kernel(
    const float* __restrict__ fmat, const float* __restrict__ att_sig,
    float* __restrict__ S) {
  int b = blockIdx.x;
  int tid = threadIdx.x;
  __shared__ float fs[NKEEP][KS + 1];
  __shared__ float as[NKEEP];
  for (int l = tid; l < NKEEP * KS; l += 256) {
    int n = l / KS, k = l % KS;
    fs[n][k] = fmat[((size_t)b * NKEEP + n) * KS + k];
  }
  if (tid < NKEEP) as[tid] = att_sig[b * NKEEP + tid];
  __syncthreads();
  for (int p = tid; p < NKEEP * NKEEP; p += 256) {
    int i = p / NKEEP, j = p % NKEEP;
    double acc = 0.0;
    for (int k = 0; k < KS; k++) acc += (double)fs[i][k] * (double)fs[j][k];
    float sc = 1.0f / (1.0f + expf(-(float)(acc * (1.0 / 16.0))));
    S[((size_t)b * NKEEP + i) * NKEEP + j] = sc * as[i] * as[j];
  }
}

// ---------------------------------------------------------------------------
// K5: Prim MST forest, one wave per batch.
__global__ __launch_bounds__(64) void prim_kernel(
    const float* __restrict__ S, int* __restrict__ parent,
    int* __restrict__ order) {
  int b = blockIdx.x;
  int lane = threadIdx.x;
  __shared__ float Ss[NKEEP * NKEEP];
  for (int l = lane; l < NKEEP * NKEEP; l += 64) Ss[l] = S[(size_t)b * NKEEP * NKEEP + l];
  __syncthreads();
  unsigned long long mask = 1ull;  // root = 0 (att sorted desc -> argmax=0)
  if (lane == 0) order[b * NKEEP + 0] = 0;
  for (int step = 1; step < NKEEP; step++) {
    float bv = -1.0f;
    int bk = NKEEP * NKEEP;
    for (int l = lane; l < NKEEP * NKEEP; l += 64) {
      int p = l / NKEEP, c = l % NKEEP;
      if (((mask >> p) & 1ull) && !((mask >> c) & 1ull)) {
        float v = Ss[l];
        if (v > bv || (v == bv && l < bk)) { bv = v; bk = l; }
      }
    }
    for (int off = 32; off > 0; off >>= 1) {
      float ov = __shfl_down(bv, off);
      int ok = __shfl_down(bk, off);
      if (ov > bv || (ov == bv && ok < bk)) { bv = ov; bk = ok; }
    }
    bk = __shfl(bk, 0);
    int p = bk / NKEEP, c = bk % NKEEP;
    mask |= (1ull << c);
    if (lane == 0) {
      parent[b * NKEEP + c] = p;
      order[b * NKEEP + step] = c;
    }
  }
}

// ---------------------------------------------------------------------------
// K6: merged f32 GEMM: [9216,2048] @ { Wx_up | Wx_dn } -> xWu / xWd.
// 128x128 tile, 8x8 per-thread microtile, Ktile=16.
__global__ __launch_bounds__(256) void gemm128(
    const float* __restrict__ A, const float* __restrict__ Wu,
    const float* __restrict__ Wd, const float* __restrict__ bu,
    const float* __restrict__ bd, float* __restrict__ Cu,
    float* __restrict__ Cd) {
  __shared__ float As[16][132];  // [k][m]
  __shared__ float Bs[16][132];  // [k][n]
  const int MT = 72, GRP = 8;
  int bid = blockIdx.x;
  int g = bid / (MT * GRP);
  int r = bid % (MT * GRP);
  int mt = r / GRP;
  int nt = g * GRP + (r % GRP);
  int m0 = mt * 128, n0g = nt * 128;
  const float* W;
  const float* bias;
  float* C;
  int n0;
  if (n0g < N4H) { W = Wu; bias = bu; C = Cu; n0 = n0g; }
  else           { W = Wd; bias = bd; C = Cd; n0 = n0g - N4H; }
  int tid = threadIdx.x;
  int tx = tid & 15, ty = tid >> 4;
  float acc[8][8];
#pragma unroll
  for (int i = 0; i < 8; i++)
#pragma unroll
    for (int j = 0; j < 8; j++) acc[i][j] = 0.0f;
  int ar = tid >> 2, akq = (tid & 3) * 4;
  int br = tid >> 5, bc = (tid & 31) * 4;
  for (int k0 = 0; k0 < DD; k0 += 16) {
    __syncthreads();
#pragma unroll
    for (int i = 0; i < 2; i++) {
      float4 av = *(const float4*)&A[(size_t)(m0 + ar + 64 * i) * DD + k0 + akq];
      As[akq + 0][ar + 64 * i] = av.x;
      As[akq + 1][ar + 64 * i] = av.y;
      As[akq + 2][ar + 64 * i] = av.z;
      As[akq + 3][ar + 64 * i] = av.w;
      *(float4*)&Bs[br + 8 * i][bc] = *(const float4*)&W[(size_t)(k0 + br + 8 * i) * N4H + n0 + bc];
    }
    __syncthreads();
#pragma unroll
    for (int kk = 0; kk < 16; kk++) {
      float4 a0 = *(const float4*)&As[kk][ty * 8];
      float4 a1 = *(const float4*)&As[kk][ty * 8 + 4];
      float4 b0 = *(const float4*)&Bs[kk][tx * 8];
      float4 b1 = *(const float4*)&Bs[kk][tx * 8 + 4];
      float am[8] = {a0.x, a0.y, a0.z, a0.w, a1.x, a1.y, a1.z, a1.w};
      float bn[8] = {b0.x, b0.y, b0.z, b0.w, b1.x, b1.y, b1.z, b1.w};
#pragma unroll
      for (int i = 0; i < 8; i++)
#pragma unroll
        for (int j = 0; j < 8; j++) acc[i][j] += am[i] * bn[j];
    }
  }
  float4 bv0 = *(const float4*)&bias[n0 + tx * 8];
  float4 bv1 = *(const float4*)&bias[n0 + tx * 8 + 4];
#pragma unroll
  for (int i = 0; i < 8; i++) {
    int row = m0 + ty * 8 + i;
    float4 o0, o1;
    o0.x = acc[i][0] + bv0.x; o0.y = acc[i][1] + bv0.y;
    o0.z = acc[i][2] + bv0.z; o0.w = acc[i][3] + bv0.w;
    o1.x = acc[i][4] + bv1.x; o1.y = acc[i][5] + bv1.y;
    o1.z = acc[i][6] + bv1.z; o1.w = acc[i][7] + bv1.w;
    *(float4*)&C[(size_t)row * N4H + n0 + tx * 8] = o0;
    *(float4*)&C[(size_t)row * N4H + n0 + tx * 8 + 4] = o1;
  }
}

// ---------------------------------------------------------------------------
// K7: one bottom-up TreeLSTM step. grid (BB/SBGB=32, H2/SKR=8), 256 threads.
// Block = 8 batches x 64 k-cols; j-reduction split 4-way across lanes (jq),
// reduced via shfl_xor. All 4 gates per (b,k) live in one thread.
__global__ __launch_bounds__(256) void up_step2(
    int t, const float* __restrict__ xW, const float* __restrict__ Wh,
    const int* __restrict__ order, const int* __restrict__ parent,
    float* __restrict__ hsum, float* __restrict__ csum,
    float* __restrict__ hup) {
  int bg = blockIdx.x, kg = blockIdx.y;
  int tid = threadIdx.x;
  int wv = tid >> 6, lane = tid & 63;
  int k4 = lane & 15, jq = lane >> 4;
  int k = kg * SKR + wv * 16 + k4;
  __shared__ float hs[SBGB][H2];
  __shared__ int nodes[SBGB], pars[SBGB];
  if (tid < SBGB) {
    int b = bg * SBGB + tid;
    int nd = order[b * NKEEP + t];
    nodes[tid] = nd;
    pars[tid] = parent[b * NKEEP + nd];
  }
  __syncthreads();
  for (int l = tid; l < SBGB * 128; l += 256) {
    int bi = l >> 7, jj = (l & 127) << 2;
    int b = bg * SBGB + bi;
    *(float4*)&hs[bi][jj] = *(const float4*)&hsum[((size_t)b * NP1 + nodes[bi]) * H2 + jj];
  }
  __syncthreads();
  float acc[SBGB][4];
#pragma unroll
  for (int bi = 0; bi < SBGB; bi++)
#pragma unroll
    for (int gg = 0; gg < 4; gg++) acc[bi][gg] = 0.0f;
  for (int j0 = 0; j0 < 128; j0 += 4) {
    int jg = jq * 128 + j0;
    float4 hv[SBGB];
#pragma unroll
    for (int bi = 0; bi < SBGB; bi++) hv[bi] = *(const float4*)&hs[bi][jg];
#pragma unroll
    for (int u = 0; u < 4; u++) {
      const float* wr = &Wh[(size_t)(jg + u) * N4H + k];
      float w0 = wr[0], w1 = wr[H2], w2 = wr[2 * H2], w3 = wr[3 * H2];
#pragma unroll
      for (int bi = 0; bi < SBGB; bi++) {
        float h = ((const float*)&hv[bi])[u];
        acc[bi][0] += h * w0;
        acc[bi][1] += h * w1;
        acc[bi][2] += h * w2;
        acc[bi][3] += h * w3;
      }
    }
  }
#pragma unroll
  for (int bi = 0; bi < SBGB; bi++)
#pragma unroll
    for (int gg = 0; gg < 4; gg++) {
      float v = acc[bi][gg];
      v += __shfl_xor(v, 16);
      v += __shfl_xor(v, 32);
      acc[bi][gg] = v;
    }
  // epilogue: lane (k4, jq) handles batches {2jq, 2jq+1} at column k
#pragma unroll
  for (int bi = 0; bi < SBGB; bi++) {
    if ((bi >> 1) != jq) continue;  // static acc index, predicated
    int b = bg * SBGB + bi;
    int nd = nodes[bi], pr = pars[bi];
    const float* xw = &xW[((size_t)b * NKEEP + nd) * N4H + k];
    float pi = acc[bi][0] + xw[0];
    float pf = acc[bi][1] + xw[H2];
    float pg = acc[bi][2] + xw[2 * H2];
    float po = acc[bi][3] + xw[3 * H2];
    float cp = csum[((size_t)b * NP1 + nd) * H2 + k];
    float c = sigf(pi) * tanhf(pg) + sigf(pf) * cp;
    float h = sigf(po) * tanhf(c);
    hup[((size_t)b * NKEEP + nd) * H2 + k] = h;
    hsum[((size_t)b * NP1 + pr) * H2 + k] += h;
    csum[((size_t)b * NP1 + pr) * H2 + k] += c;
  }
}

// ---------------------------------------------------------------------------
// K8: one top-down TreeLSTM step (same structure; reads parent state).
__global__ __launch_bounds__(256) void dn_step2(
    int t, const float* __restrict__ xW, const float* __restrict__ Wh,
    const int* __restrict__ order, const int* __restrict__ parent,
    float* __restrict__ hd, float* __restrict__ cd) {
  int bg = blockIdx.x, kg = blockIdx.y;
  int tid = threadIdx.x;
  int wv = tid >> 6, lane = tid & 63;
  int k4 = lane & 15, jq = lane >> 4;
  int k = kg * SKR + wv * 16 + k4;
  __shared__ float hs[SBGB][H2];
  __shared__ int nodes[SBGB], pars[SBGB];
  if (tid < SBGB) {
    int b = bg * SBGB + tid;
    int nd = order[b * NKEEP + t];
    nodes[tid] = nd;
    pars[tid] = parent[b * NKEEP + nd];
  }
  __syncthreads();
  for (int l = tid; l < SBGB * 128; l += 256) {
    int bi = l >> 7, jj = (l & 127) << 2;
    int b = bg * SBGB + bi;
    *(float4*)&hs[bi][jj] = *(const float4*)&hd[((size_t)b * NP1 + pars[bi]) * H2 + jj];
  }
  __syncthreads();
  float acc[SBGB][4];
#pragma unroll
  for (int bi = 0; bi < SBGB; bi++)
#pragma unroll
    for (int gg = 0; gg < 4; gg++) acc[bi][gg] = 0.0f;
  for (int j0 = 0; j0 < 128; j0 += 4) {
    int jg = jq * 128 + j0;
    float4 hv[SBGB];
#pragma unroll
    for (int bi = 0; bi < SBGB; bi++) hv[bi] = *(const float4*)&hs[bi][jg];
#pragma unroll
    for (int u = 0; u < 4; u++) {
      const float* wr = &Wh[(size_t)(jg + u) * N4H + k];
      float w0 = wr[0], w1 = wr[H2], w2 = wr[2 * H2], w3 = wr[3 * H2];
#pragma unroll
      for (int bi = 0; bi < SBGB; bi++) {
        float h = ((const float*)&hv[bi])[u];
        acc[bi][0] += h * w0;
        acc[bi][1] += h * w1;
        acc[bi][2] += h * w2;
        acc[bi][3] += h * w3;
      }
    }
  }
#pragma unroll
  for (int bi = 0; bi < SBGB; bi++)
#pragma unroll
    for (int gg = 0; gg < 4; gg++) {
      float v = acc[bi][gg];
      v += __shfl_xor(v, 16);
      v += __shfl_xor(v, 32);
      acc[bi][gg] = v;
    }
#pragma unroll
  for (int bi = 0; bi < SBGB; bi++) {
    if ((bi >> 1) != jq) continue;
    int b = bg * SBGB + bi;
    int nd = nodes[bi], pr = pars[bi];
    const float* xw = &xW[((size_t)b * NKEEP + nd) * N4H + k];
    float pi = acc[bi][0] + xw[0];
    float pf = acc[bi][1] + xw[H2];
    float pg = acc[bi][2] + xw[2 * H2];
    float po = acc[bi][3] + xw[3 * H2];
    float cp = cd[((size_t)b * NP1 + pr) * H2 + k];
    float c = sigf(pi) * tanhf(pg) + sigf(pf) * cp;
    float h = sigf(po) * tanhf(c);
    hd[((size_t)b * NP1 + nd) * H2 + k] = h;
    cd[((size_t)b * NP1 + nd) * H2 + k] = c;
  }
}

// ---------------------------------------------------------------------------
// K9: out[b][q][n] = q<512 ? hup[b][n][q] : hd[b][n][q-512]
__global__ __launch_bounds__(256) void out_transpose(
    const float* __restrict__ hup, const float* __restrict__ hd,
    float* __restrict__ out) {
  int b = blockIdx.x;
  __shared__ float s[NKEEP][65];
  for (int half = 0; half < 2; half++) {
    const float* src = half ? hd : hup;
    int rs = half ? NP1 : NKEEP;
    for (int q0 = 0; q0 < H2; q0 += 64) {
      __syncthreads();
      for (int l = threadIdx.x; l < NKEEP * 64; l += 256) {
        int n = l / 64, qq = l % 64;
        s[n][qq] = src[((size_t)b * rs + n) * H2 + q0 + qq];
      }
      __syncthreads();
      for (int l = threadIdx.x; l < NKEEP * 64; l += 256) {
        int qq = l / NKEEP, n = l % NKEEP;
        out[(size_t)b * (HID * NKEEP) + (half * H2 + q0 + qq) * NKEEP + n] = s[n][qq];
      }
    }
  }
}

// ---------------------------------------------------------------------------
extern "C" void kernel_launch(void* const* d_in, const int* in_sizes, int n_in,
                              void* d_out, int out_size, void* d_ws, size_t ws_size,
                              hipStream_t stream) {
  const float* boxes = (const float*)d_in[0];
  const float* attention = (const float*)d_in[1];
  const float* vf = (const float*)d_in[2];
  const float* vo = (const float*)d_in[3];
  const float* Wv = (const float*)d_in[5];
  const float* Wb = (const float*)d_in[6];
  const float* Wx_up = (const float*)d_in[7];
  const float* Wh_up = (const float*)d_in[8];
  const float* b_up = (const float*)d_in[9];
  const float* Wx_dn = (const float*)d_in[10];
  const float* Wh_dn = (const float*)d_in[11];
  const float* b_dn = (const float*)d_in[12];
  float* out = (float*)d_out;

  char* ws = (char*)d_ws;
  size_t off = 0;
  auto take = [&](size_t bytes) -> char* {
    char* p = ws + off;
    off = (off + bytes + 255) & ~(size_t)255;
    return p;
  };
  int* idx = (int*)take((size_t)BB * NKEEP * 4);
  float* att_sig = (float*)take((size_t)BB * NKEEP * 4);
  float* bxk = (float*)take((size_t)BB * NKEEP * 4 * 4);
  int* parent = (int*)take((size_t)BB * NKEEP * 4);
  int* order = (int*)take((size_t)BB * NKEEP * 4);
  float* fmat = (float*)take((size_t)BB * NKEEP * KS * 4);
  float* S = (float*)take((size_t)BB * NKEEP * NKEEP * 4);
  float* x = (float*)take((size_t)BB * NKEEP * DD * 4);
  float* xWu = (float*)take((size_t)BB * NKEEP * N4H * 4);
  float* xWd = (float*)take((size_t)BB * NKEEP * N4H * 4);
  float* hsum = (float*)take((size_t)BB * NP1 * H2 * 4);
  float* csum = (float*)take((size_t)BB * NP1 * H2 * 4);
  float* hd = (float*)take((size_t)BB * NP1 * H2 * 4);
  float* cd = (float*)take((size_t)BB * NP1 * H2 * 4);
  float* hup = x;  // alias: x is dead after the big GEMM

  topk_kernel<<<BB, 128, 0, stream>>>(attention, boxes, idx, att_sig, bxk, parent);
  gather_x<<<dim3(BB, DD / 32), 256, 0, stream>>>(vf, idx, x);
  f_kernel<<<BB, 256, 0, stream>>>(vo, Wv, Wb, idx, bxk, fmat);
  s_kernel<<<BB, 256, 0, stream>>>(fmat, att_sig, S);
  prim_kernel<<<BB, 64, 0, stream>>>(S, parent, order);

  // merged GEMM over N=4096 (up|dn): 72 x 32 tiles of 128x128
  gemm128<<<72 * 32, 256, 0, stream>>>(x, Wx_up, Wx_dn, b_up, b_dn, xWu, xWd);

  size_t accb = (size_t)BB * NP1 * H2 * 4;
  hipMemsetAsync(hsum, 0, accb * 4, stream);  // hsum,csum,hd,cd contiguous

  for (int t = NKEEP - 1; t >= 0; --t)
    up_step2<<<dim3(BB / SBGB, H2 / SKR), 256, 0, stream>>>(t, xWu, Wh_up, order, parent, hsum, csum, hup);
  for (int t = 0; t < NKEEP; ++t)
    dn_step2<<<dim3(BB / SBGB, H2 / SKR), 256, 0, stream>>>(t, xWd, Wh_dn, order, parent, hd, cd);

  out_transpose<<<BB, 256, 0, stream>>>(hup, hd, out);
}

// Round 3
// 2987.109 us; speedup vs baseline: 2.7016x; 1.5972x over previous
//
#include <hip/hip_runtime.h>
#include <math.h>

// Problem constants (match reference)
#define BB 256
#define NOBJ 100
#define NKEEP 36
#define DD 2048
#define HID 1024
#define KS 256
#define H2 512
#define NP1 (NKEEP + 1)
#define N4H 2048   // 4*H2
#define SBGB 4     // batches per block in step kernels
#define SKR 64     // k-columns per block in step kernels

typedef __attribute__((ext_vector_type(8))) short short8v;
typedef __attribute__((ext_vector_type(4))) float f32x4;
typedef unsigned short ushort_t;
typedef unsigned int uint_t;

__device__ __forceinline__ float sigf(float x) { return 1.0f / (1.0f + expf(-x)); }
// f32 -> bf16 round-to-nearest-even (bit manip, deterministic)
__device__ __forceinline__ ushort_t f2b(float f) {
  uint_t u = __float_as_uint(f);
  uint_t r = (u + 0x7FFFu + ((u >> 16) & 1u)) >> 16;
  return (ushort_t)r;
}
__device__ __forceinline__ float b2f(ushort_t u) {
  return __uint_as_float(((uint_t)u) << 16);
}

#define GLOAD_LDS16(gp, lp)                                                   \
  __builtin_amdgcn_global_load_lds(                                           \
      (const __attribute__((address_space(1))) void*)(gp),                    \
      (__attribute__((address_space(3))) void*)(lp), 16, 0, 0)

// ---------------------------------------------------------------------------
// K1: per-batch top-NKEEP by attention (stable, descending), gather boxes.
__global__ __launch_bounds__(128) void topk_kernel(
    const float* __restrict__ att, const float* __restrict__ boxes,
    int* __restrict__ idx, float* __restrict__ att_sig,
    float* __restrict__ bxk, int* __restrict__ parent) {
  int b = blockIdx.x;
  int t = threadIdx.x;
  __shared__ float a[NOBJ];
  if (t < NOBJ) a[t] = att[b * NOBJ + t];
  __syncthreads();
  if (t < NOBJ) {
    float ai = a[t];
    int rank = 0;
    for (int j = 0; j < NOBJ; j++) {
      float aj = a[j];
      rank += (aj > ai) || (aj == ai && j < t);
    }
    if (rank < NKEEP) {
      idx[b * NKEEP + rank] = t;
      att_sig[b * NKEEP + rank] = 1.0f / (1.0f + expf(-ai));
      for (int c = 0; c < 4; c++)
        bxk[(b * NKEEP + rank) * 4 + c] = boxes[(b * 4 + c) * NOBJ + t];
    }
  }
  if (t < NKEEP) parent[b * NKEEP + t] = NKEEP;  // sentinel
}

// ---------------------------------------------------------------------------
// K2: gather + split x into A' (fragment-major bf16 [mt][128 ks][g][lane][j]).
// phys ksteps: 0-63 = hi(d), 64-127 = lo(d).
__global__ __launch_bounds__(256) void gather_x(
    const float* __restrict__ vf, const int* __restrict__ idx,
    ushort_t* __restrict__ A2) {
  int b = blockIdx.x;
  int ksh = blockIdx.y;       // = d0/32
  int d0 = ksh * 32;
  __shared__ float s[32][101];
  __shared__ int idxs[NKEEP];
  int tid = threadIdx.x;
  if (tid < NKEEP) idxs[tid] = idx[b * NKEEP + tid];
  for (int l = tid; l < 32 * NOBJ; l += 256) {
    int dd = l / NOBJ, c = l % NOBJ;
    s[dd][c] = vf[((size_t)b * DD + d0 + dd) * NOBJ + c];
  }
  __syncthreads();
  for (int l = tid; l < NKEEP * 32; l += 256) {
    int n = l >> 5, dd = l & 31;
    float v = s[dd][idxs[n]];
    int m = b * NKEEP + n;
    int mt = m >> 7, r = m & 127, g = r >> 4, row16 = r & 15;
    int q = dd >> 3, j = dd & 7;
    int lane = row16 + (q << 4);
    size_t base = ((size_t)mt * 128 + ksh) * 4096 + g * 512 + lane * 8 + j;
    ushort_t hi = f2b(v);
    ushort_t lo = f2b(v - b2f(hi));
    A2[base] = hi;
    A2[base + (size_t)64 * 4096] = lo;
  }
}

// ---------------------------------------------------------------------------
// K3: f[b][n][k] = tanh(sum_d vo[b,d,idx[n]]*Wv[d,k] + sum_c bx*Wb) (f32)
__global__ __launch_bounds__(256) void f_kernel(
    const float* __restrict__ vo, const float* __restrict__ Wv,
    const float* __restrict__ Wb, const int* __restrict__ idx,
    const float* __restrict__ bxk, float* __restrict__ fmat) {
  int b = blockIdx.x;
  int k = threadIdx.x;  // 0..255
  __shared__ int idxs[NKEEP];
  __shared__ float vs[16][NKEEP];
  if (k < NKEEP) idxs[k] = idx[b * NKEEP + k];
  __syncthreads();
  float acc[NKEEP];
#pragma unroll
  for (int n = 0; n < NKEEP; n++) acc[n] = 0.0f;
  for (int d0 = 0; d0 < DD; d0 += 16) {
    __syncthreads();
    for (int l = k; l < 16 * NKEEP; l += 256) {
      int dd = l / NKEEP, n = l % NKEEP;
      vs[dd][n] = vo[((size_t)b * DD + d0 + dd) * NOBJ + idxs[n]];
    }
    __syncthreads();
#pragma unroll
    for (int dd = 0; dd < 16; dd++) {
      float w = Wv[(size_t)(d0 + dd) * KS + k];
#pragma unroll
      for (int n = 0; n < NKEEP; n++) acc[n] += vs[dd][n] * w;
    }
  }
  for (int n = 0; n < NKEEP; n++) {
    float s = acc[n];
#pragma unroll
    for (int c = 0; c < 4; c++) s += bxk[(b * NKEEP + n) * 4 + c] * Wb[c * KS + k];
    fmat[((size_t)b * NKEEP + n) * KS + k] = tanhf(s);
  }
}

// ---------------------------------------------------------------------------
// K4: S[b][i][j] = sigmoid((f_i . f_j)/16) * att_i * att_j   (f64 accum)
__global__ __launch_bounds__(256) void s_kernel(
    const float* __restrict__ fmat, const float* __restrict__ att_sig,
    float* __restrict__ S) {
  int b = blockIdx.x;
  int tid = threadIdx.x;
  __shared__ float fs[NKEEP][KS + 1];
  __shared__ float as[NKEEP];
  for (int l = tid; l < NKEEP * KS; l += 256) {
    int n = l / KS, k = l % KS;
    fs[n][k] = fmat[((size_t)b * NKEEP + n) * KS + k];
  }
  if (tid < NKEEP) as[tid] = att_sig[b * NKEEP + tid];
  __syncthreads();
  for (int p = tid; p < NKEEP * NKEEP; p += 256) {
    int i = p / NKEEP, j = p % NKEEP;
    double acc = 0.0;
    for (int k = 0; k < KS; k++) acc += (double)fs[i][k] * (double)fs[j][k];
    float sc = 1.0f / (1.0f + expf(-(float)(acc * (1.0 / 16.0))));
    S[((size_t)b * NKEEP + i) * NKEEP + j] = sc * as[i] * as[j];
  }
}

// ---------------------------------------------------------------------------
// K5: Prim MST forest, one wave per batch.
__global__ __launch_bounds__(64) void prim_kernel(
    const float* __restrict__ S, int* __restrict__ parent,
    int* __restrict__ order) {
  int b = blockIdx.x;
  int lane = threadIdx.x;
  __shared__ float Ss[NKEEP * NKEEP];
  for (int l = lane; l < NKEEP * NKEEP; l += 64) Ss[l] = S[(size_t)b * NKEEP * NKEEP + l];
  __syncthreads();
  unsigned long long mask = 1ull;  // root = 0 (att sorted desc -> argmax=0)
  if (lane == 0) order[b * NKEEP + 0] = 0;
  for (int step = 1; step < NKEEP; step++) {
    float bv = -1.0f;
    int bk = NKEEP * NKEEP;
    for (int l = lane; l < NKEEP * NKEEP; l += 64) {
      int p = l / NKEEP, c = l % NKEEP;
      if (((mask >> p) & 1ull) && !((mask >> c) & 1ull)) {
        float v = Ss[l];
        if (v > bv || (v == bv && l < bk)) { bv = v; bk = l; }
      }
    }
    for (int off = 32; off > 0; off >>= 1) {
      float ov = __shfl_down(bv, off);
      int ok = __shfl_down(bk, off);
      if (ov > bv || (ov == bv && ok < bk)) { bv = ov; bk = ok; }
    }
    bk = __shfl(bk, 0);
    int p = bk / NKEEP, c = bk % NKEEP;
    mask |= (1ull << c);
    if (lane == 0) {
      parent[b * NKEEP + c] = p;
      order[b * NKEEP + step] = c;
    }
  }
}

// ---------------------------------------------------------------------------
// K6a: build W' fragment-major bf16: [nt:32][ks:128][h:8][lane:64][j:8].
// phys ks 0-63 = W_hi rows, 64-127 = W_lo rows. nt<16 -> Wu, else Wd.
__global__ __launch_bounds__(256) void wconv(
    const float* __restrict__ Wu, const float* __restrict__ Wd,
    ushort_t* __restrict__ B2) {
  int nt = blockIdx.x;   // 0..31
  int ks = blockIdx.y;   // 0..127
  int tid = threadIdx.x;
  const float* W = (nt < 16) ? Wu : Wd;
  int n0 = (nt & 15) * 128;
  int k0 = (ks & 63) * 32;
  bool is_hi = (ks < 64);
  __shared__ float tile[32][129];
  for (int l = tid; l < 32 * 128; l += 256) {
    int kk = l >> 7, c = l & 127;
    tile[kk][c] = W[(size_t)(k0 + kk) * N4H + n0 + c];
  }
  __syncthreads();
  size_t obase = ((size_t)nt * 128 + ks) * 4096 + tid * 16;
#pragma unroll
  for (int u = 0; u < 16; u++) {
    int e = tid * 16 + u;
    int h = e >> 9;
    int lane = (e >> 3) & 63;
    int j = e & 7;
    int c = h * 16 + (lane & 15);
    int kk = (lane >> 4) * 8 + j;
    float v = tile[kk][c];
    ushort_t o;
    if (is_hi) o = f2b(v);
    else { ushort_t hi = f2b(v); o = f2b(v - b2f(hi)); }
    B2[obase + u] = o;
  }
}

// K6b: elementwise f32 -> bf16 (for Wh)
__global__ __launch_bounds__(256) void bf16conv(
    const float* __restrict__ src, ushort_t* __restrict__ dst, int n) {
  int i = blockIdx.x * 256 + threadIdx.x;
  if (i < n) dst[i] = f2b(src[i]);
}

// ---------------------------------------------------------------------------
// K6: MFMA split-bf16 GEMM. M=9216 (72 mt), N=4096 (32 nt), K'=6144 (192 s).
// logical s -> A phys kstep: s<128 ? s : s-128 ; B phys: s<64 ? s : s-64.
// 128x128 tile, 4 waves in 2x2, each wave 64x64 = 4x4 frags of 16x16x32.
__global__ __launch_bounds__(256) void mfma_gemm(
    const ushort_t* __restrict__ A2, const ushort_t* __restrict__ B2,
    const float* __restrict__ bu, const float* __restrict__ bd,
    float* __restrict__ Cu, float* __restrict__ Cd) {
  __shared__ __align__(16) ushort_t Asl[4096];  // 8KB: 8 chunks of 1KB
  __shared__ __align__(16) ushort_t Bsl[4096];
  int bid = blockIdx.x;
  int nt = bid & 31;
  int mt = bid >> 5;
  int tid = threadIdx.x;
  int w = tid >> 6, lane = tid & 63;
  int wr = w >> 1, wc = w & 1;
  f32x4 acc[4][4];
#pragma unroll
  for (int i = 0; i < 4; i++)
#pragma unroll
    for (int j = 0; j < 4; j++) acc[i][j] = (f32x4){0.f, 0.f, 0.f, 0.f};
  const size_t Abase = (size_t)mt * 128 * 4096;
  const size_t Bbase = (size_t)nt * 128 * 4096;
  for (int s = 0; s < 192; ++s) {
    int aks = (s < 128) ? s : s - 128;
    int bks = (s < 64) ? s : s - 64;
    const ushort_t* ag = A2 + Abase + (size_t)aks * 4096 + (w * 2) * 512 + lane * 8;
    const ushort_t* bg = B2 + Bbase + (size_t)bks * 4096 + (w * 2) * 512 + lane * 8;
    __syncthreads();
    GLOAD_LDS16(ag, &Asl[(w * 2) * 512]);
    GLOAD_LDS16(ag + 512, &Asl[(w * 2 + 1) * 512]);
    GLOAD_LDS16(bg, &Bsl[(w * 2) * 512]);
    GLOAD_LDS16(bg + 512, &Bsl[(w * 2 + 1) * 512]);
    __syncthreads();
    short8v a[4], bfr[4];
#pragma unroll
    for (int mi = 0; mi < 4; mi++)
      a[mi] = *(const short8v*)&Asl[(wr * 4 + mi) * 512 + lane * 8];
#pragma unroll
    for (int ni = 0; ni < 4; ni++)
      bfr[ni] = *(const short8v*)&Bsl[(wc * 4 + ni) * 512 + lane * 8];
#pragma unroll
    for (int mi = 0; mi < 4; mi++)
#pragma unroll
      for (int ni = 0; ni < 4; ni++)
        acc[mi][ni] = __builtin_amdgcn_mfma_f32_16x16x32_bf16(
            a[mi], bfr[ni], acc[mi][ni], 0, 0, 0);
  }
  // epilogue: C/D map col=lane&15, row=(lane>>4)*4+reg  [m89-verified]
  int col16 = lane & 15, rq = lane >> 4;
#pragma unroll
  for (int ni = 0; ni < 4; ni++) {
    int nglob = nt * 128 + wc * 64 + ni * 16 + col16;
    const float* bias = (nt < 16) ? bu : bd;
    float* C = (nt < 16) ? Cu : Cd;
    int nn = (nt < 16) ? nglob : nglob - N4H;
    float bv = bias[nn];
#pragma unroll
    for (int mi = 0; mi < 4; mi++) {
#pragma unroll
      for (int r = 0; r < 4; r++) {
        int m = mt * 128 + wr * 64 + mi * 16 + rq * 4 + r;
        C[(size_t)m * N4H + nn] = acc[mi][ni][r] + bv;
      }
    }
  }
}

// ---------------------------------------------------------------------------
// K7: one bottom-up TreeLSTM step. grid (BB/SBGB=64, H2/SKR=8), 256 threads.
// Block = 4 batches x 64 k-cols; j-reduction split 4-way across lanes (jq),
// reduced via shfl_xor. Wh in bf16.
__global__ __launch_bounds__(256) void up_step2(
    int t, const float* __restrict__ xW, const ushort_t* __restrict__ Wh,
    const int* __restrict__ order, const int* __restrict__ parent,
    float* __restrict__ hsum, float* __restrict__ csum,
    float* __restrict__ hup) {
  int bg = blockIdx.x, kg = blockIdx.y;
  int tid = threadIdx.x;
  int wv = tid >> 6, lane = tid & 63;
  int k4 = lane & 15, jq = lane >> 4;
  int k = kg * SKR + wv * 16 + k4;
  __shared__ float hs[SBGB][H2];
  __shared__ int nodes[SBGB], pars[SBGB];
  if (tid < SBGB) {
    int b = bg * SBGB + tid;
    int nd = order[b * NKEEP + t];
    nodes[tid] = nd;
    pars[tid] = parent[b * NKEEP + nd];
  }
  __syncthreads();
  for (int l = tid; l < SBGB * 128; l += 256) {
    int bi = l >> 7, jj = (l & 127) << 2;
    int b = bg * SBGB + bi;
    *(float4*)&hs[bi][jj] = *(const float4*)&hsum[((size_t)b * NP1 + nodes[bi]) * H2 + jj];
  }
  __syncthreads();
  float acc[SBGB][4];
#pragma unroll
  for (int bi = 0; bi < SBGB; bi++)
#pragma unroll
    for (int gg = 0; gg < 4; gg++) acc[bi][gg] = 0.0f;
  for (int j0 = 0; j0 < 128; j0 += 4) {
    int jg = jq * 128 + j0;
    float4 hv[SBGB];
#pragma unroll
    for (int bi = 0; bi < SBGB; bi++) hv[bi] = *(const float4*)&hs[bi][jg];
#pragma unroll
    for (int u = 0; u < 4; u++) {
      const ushort_t* wr = &Wh[(size_t)(jg + u) * N4H + k];
      float w0 = b2f(wr[0]), w1 = b2f(wr[H2]), w2 = b2f(wr[2 * H2]), w3 = b2f(wr[3 * H2]);
#pragma unroll
      for (int bi = 0; bi < SBGB; bi++) {
        float h = ((const float*)&hv[bi])[u];
        acc[bi][0] += h * w0;
        acc[bi][1] += h * w1;
        acc[bi][2] += h * w2;
        acc[bi][3] += h * w3;
      }
    }
  }
#pragma unroll
  for (int bi = 0; bi < SBGB; bi++)
#pragma unroll
    for (int gg = 0; gg < 4; gg++) {
      float v = acc[bi][gg];
      v += __shfl_xor(v, 16);
      v += __shfl_xor(v, 32);
      acc[bi][gg] = v;
    }
#pragma unroll
  for (int bi = 0; bi < SBGB; bi++) {
    if (bi != jq) continue;  // lane's jq owns batch bi
    int b = bg * SBGB + bi;
    int nd = nodes[bi], pr = pars[bi];
    const float* xw = &xW[((size_t)b * NKEEP + nd) * N4H + k];
    float pi = acc[bi][0] + xw[0];
    float pf = acc[bi][1] + xw[H2];
    float pg = acc[bi][2] + xw[2 * H2];
    float po = acc[bi][3] + xw[3 * H2];
    float cp = csum[((size_t)b * NP1 + nd) * H2 + k];
    float c = sigf(pi) * tanhf(pg) + sigf(pf) * cp;
    float h = sigf(po) * tanhf(c);
    hup[((size_t)b * NKEEP + nd) * H2 + k] = h;
    hsum[((size_t)b * NP1 + pr) * H2 + k] += h;
    csum[((size_t)b * NP1 + pr) * H2 + k] += c;
  }
}

// ---------------------------------------------------------------------------
// K8: one top-down TreeLSTM step (reads parent state).
__global__ __launch_bounds__(256) void dn_step2(
    int t, const float* __restrict__ xW, const ushort_t* __restrict__ Wh,
    const int* __restrict__ order, const int* __restrict__ parent,
    float* __restrict__ hd, float* __restrict__ cd) {
  int bg = blockIdx.x, kg = blockIdx.y;
  int tid = threadIdx.x;
  int wv = tid >> 6, lane = tid & 63;
  int k4 = lane & 15, jq = lane >> 4;
  int k = kg * SKR + wv * 16 + k4;
  __shared__ float hs[SBGB][H2];
  __shared__ int nodes[SBGB], pars[SBGB];
  if (tid < SBGB) {
    int b = bg * SBGB + tid;
    int nd = order[b * NKEEP + t];
    nodes[tid] = nd;
    pars[tid] = parent[b * NKEEP + nd];
  }
  __syncthreads();
  for (int l = tid; l < SBGB * 128; l += 256) {
    int bi = l >> 7, jj = (l & 127) << 2;
    int b = bg * SBGB + bi;
    *(float4*)&hs[bi][jj] = *(const float4*)&hd[((size_t)b * NP1 + pars[bi]) * H2 + jj];
  }
  __syncthreads();
  float acc[SBGB][4];
#pragma unroll
  for (int bi = 0; bi < SBGB; bi++)
#pragma unroll
    for (int gg = 0; gg < 4; gg++) acc[bi][gg] = 0.0f;
  for (int j0 = 0; j0 < 128; j0 += 4) {
    int jg = jq * 128 + j0;
    float4 hv[SBGB];
#pragma unroll
    for (int bi = 0; bi < SBGB; bi++) hv[bi] = *(const float4*)&hs[bi][jg];
#pragma unroll
    for (int u = 0; u < 4; u++) {
      const ushort_t* wr = &Wh[(size_t)(jg + u) * N4H + k];
      float w0 = b2f(wr[0]), w1 = b2f(wr[H2]), w2 = b2f(wr[2 * H2]), w3 = b2f(wr[3 * H2]);
#pragma unroll
      for (int bi = 0; bi < SBGB; bi++) {
        float h = ((const float*)&hv[bi])[u];
        acc[bi][0] += h * w0;
        acc[bi][1] += h * w1;
        acc[bi][2] += h * w2;
        acc[bi][3] += h * w3;
      }
    }
  }
#pragma unroll
  for (int bi = 0; bi < SBGB; bi++)
#pragma unroll
    for (int gg = 0; gg < 4; gg++) {
      float v = acc[bi][gg];
      v += __shfl_xor(v, 16);
      v += __shfl_xor(v, 32);
      acc[bi][gg] = v;
    }
#pragma unroll
  for (int bi = 0; bi < SBGB; bi++) {
    if (bi != jq) continue;
    int b = bg * SBGB + bi;
    int nd = nodes[bi], pr = pars[bi];
    const float* xw = &xW[((size_t)b * NKEEP + nd) * N4H + k];
    float pi = acc[bi][0] + xw[0];
    float pf = acc[bi][1] + xw[H2];
    float pg = acc[bi][2] + xw[2 * H2];
    float po = acc[bi][3] + xw[3 * H2];
    float cp = cd[((size_t)b * NP1 + pr) * H2 + k];
    float c = sigf(pi) * tanhf(pg) + sigf(pf) * cp;
    float h = sigf(po) * tanhf(c);
    hd[((size_t)b * NP1 + nd) * H2 + k] = h;
    cd[((size_t)b * NP1 + nd) * H2 + k] = c;
  }
}

// ---------------------------------------------------------------------------
// K9: out[b][q][n] = q<512 ? hup[b][n][q] : hd[b][n][q-512]
__global__ __launch_bounds__(256) void out_transpose(
    const float* __restrict__ hup, const float* __restrict__ hd,
    float* __restrict__ out) {
  int b = blockIdx.x;
  __shared__ float s[NKEEP][65];
  for (int half = 0; half < 2; half++) {
    const float* src = half ? hd : hup;
    int rs = half ? NP1 : NKEEP;
    for (int q0 = 0; q0 < H2; q0 += 64) {
      __syncthreads();
      for (int l = threadIdx.x; l < NKEEP * 64; l += 256) {
        int n = l / 64, qq = l % 64;
        s[n][qq] = src[((size_t)b * rs + n) * H2 + q0 + qq];
      }
      __syncthreads();
      for (int l = threadIdx.x; l < NKEEP * 64; l += 256) {
        int qq = l / NKEEP, n = l % NKEEP;
        out[(size_t)b * (HID * NKEEP) + (half * H2 + q0 + qq) * NKEEP + n] = s[n][qq];
      }
    }
  }
}

// ---------------------------------------------------------------------------
extern "C" void kernel_launch(void* const* d_in, const int* in_sizes, int n_in,
                              void* d_out, int out_size, void* d_ws, size_t ws_size,
                              hipStream_t stream) {
  const float* boxes = (const float*)d_in[0];
  const float* attention = (const float*)d_in[1];
  const float* vf = (const float*)d_in[2];
  const float* vo = (const float*)d_in[3];
  const float* Wv = (const float*)d_in[5];
  const float* Wb = (const float*)d_in[6];
  const float* Wx_up = (const float*)d_in[7];
  const float* Wh_up = (const float*)d_in[8];
  const float* b_up = (const float*)d_in[9];
  const float* Wx_dn = (const float*)d_in[10];
  const float* Wh_dn = (const float*)d_in[11];
  const float* b_dn = (const float*)d_in[12];
  float* out = (float*)d_out;

  char* ws = (char*)d_ws;
  size_t off = 0;
  auto take = [&](size_t bytes) -> char* {
    char* p = ws + off;
    off = (off + bytes + 255) & ~(size_t)255;
    return p;
  };
  int* idx = (int*)take((size_t)BB * NKEEP * 4);
  float* att_sig = (float*)take((size_t)BB * NKEEP * 4);
  float* bxk = (float*)take((size_t)BB * NKEEP * 4 * 4);
  int* parent = (int*)take((size_t)BB * NKEEP * 4);
  int* order = (int*)take((size_t)BB * NKEEP * 4);
  float* fmat = (float*)take((size_t)BB * NKEEP * KS * 4);
  float* S = (float*)take((size_t)BB * NKEEP * NKEEP * 4);
  ushort_t* A2 = (ushort_t*)take((size_t)72 * 128 * 4096 * 2);     // 75.5 MB
  ushort_t* B2 = (ushort_t*)take((size_t)32 * 128 * 4096 * 2);     // 33.6 MB
  float* xWu = (float*)take((size_t)BB * NKEEP * N4H * 4);
  float* xWd = (float*)take((size_t)BB * NKEEP * N4H * 4);
  float* hsum = (float*)take((size_t)BB * NP1 * H2 * 4);
  float* csum = (float*)take((size_t)BB * NP1 * H2 * 4);
  float* hd = (float*)take((size_t)BB * NP1 * H2 * 4);
  float* cd = (float*)take((size_t)BB * NP1 * H2 * 4);
  ushort_t* Whu_b = (ushort_t*)take((size_t)H2 * N4H * 2);
  ushort_t* Whd_b = (ushort_t*)take((size_t)H2 * N4H * 2);
  float* hup = (float*)A2;  // alias: A2 dead after mfma_gemm

  topk_kernel<<<BB, 128, 0, stream>>>(attention, boxes, idx, att_sig, bxk, parent);
  gather_x<<<dim3(BB, 64), 256, 0, stream>>>(vf, idx, A2);
  f_kernel<<<BB, 256, 0, stream>>>(vo, Wv, Wb, idx, bxk, fmat);
  s_kernel<<<BB, 256, 0, stream>>>(fmat, att_sig, S);
  prim_kernel<<<BB, 64, 0, stream>>>(S, parent, order);

  wconv<<<dim3(32, 128), 256, 0, stream>>>(Wx_up, Wx_dn, B2);
  int whn = H2 * N4H;
  bf16conv<<<(whn + 255) / 256, 256, 0, stream>>>(Wh_up, Whu_b, whn);
  bf16conv<<<(whn + 255) / 256, 256, 0, stream>>>(Wh_dn, Whd_b, whn);

  mfma_gemm<<<72 * 32, 256, 0, stream>>>(A2, B2, b_up, b_dn, xWu, xWd);

  size_t accb = (size_t)BB * NP1 * H2 * 4;
  hipMemsetAsync(hsum, 0, accb * 4, stream);  // hsum,csum,hd,cd contiguous

  for (int t = NKEEP - 1; t >= 0; --t)
    up_step2<<<dim3(BB / SBGB, H2 / SKR), 256, 0, stream>>>(t, xWu, Whu_b, order, parent, hsum, csum, hup);
  for (int t = 0; t < NKEEP; ++t)
    dn_step2<<<dim3(BB / SBGB, H2 / SKR), 256, 0, stream>>>(t, xWd, Whd_b, order, parent, hd, cd);

  out_transpose<<<BB, 256, 0, stream>>>(hup, hd, out);
}

// Round 4
// 1726.377 us; speedup vs baseline: 4.6746x; 1.7303x over previous
//
#include <hip/hip_runtime.h>
#include <math.h>

// Problem constants (match reference)
#define BB 256
#define NOBJ 100
#define NKEEP 36
#define DD 2048
#define HID 1024
#define KS 256
#define H2 512
#define NP1 (NKEEP + 1)
#define N4H 2048   // 4*H2

typedef __attribute__((ext_vector_type(8))) short short8v;
typedef __attribute__((ext_vector_type(4))) float f32x4;
typedef unsigned short ushort_t;
typedef unsigned int uint_t;

__device__ __forceinline__ float sigf(float x) { return 1.0f / (1.0f + expf(-x)); }
// f32 -> bf16 round-to-nearest-even (bit manip, deterministic)
__device__ __forceinline__ ushort_t f2b(float f) {
  uint_t u = __float_as_uint(f);
  uint_t r = (u + 0x7FFFu + ((u >> 16) & 1u)) >> 16;
  return (ushort_t)r;
}
__device__ __forceinline__ float b2f(ushort_t u) {
  return __uint_as_float(((uint_t)u) << 16);
}
__device__ __forceinline__ short8v pack8(float4 a, float4 b) {
  short8v p;
  p[0] = (short)f2b(a.x); p[1] = (short)f2b(a.y);
  p[2] = (short)f2b(a.z); p[3] = (short)f2b(a.w);
  p[4] = (short)f2b(b.x); p[5] = (short)f2b(b.y);
  p[6] = (short)f2b(b.z); p[7] = (short)f2b(b.w);
  return p;
}

#define GLOAD_LDS16(gp, lp)                                                   \
  __builtin_amdgcn_global_load_lds(                                           \
      (const __attribute__((address_space(1))) void*)(gp),                    \
      (__attribute__((address_space(3))) void*)(lp), 16, 0, 0)

// ---------------------------------------------------------------------------
// K1: per-batch top-NKEEP by attention (stable, descending), gather boxes.
__global__ __launch_bounds__(128) void topk_kernel(
    const float* __restrict__ att, const float* __restrict__ boxes,
    int* __restrict__ idx, float* __restrict__ att_sig,
    float* __restrict__ bxk, int* __restrict__ parent) {
  int b = blockIdx.x;
  int t = threadIdx.x;
  __shared__ float a[NOBJ];
  if (t < NOBJ) a[t] = att[b * NOBJ + t];
  __syncthreads();
  if (t < NOBJ) {
    float ai = a[t];
    int rank = 0;
    for (int j = 0; j < NOBJ; j++) {
      float aj = a[j];
      rank += (aj > ai) || (aj == ai && j < t);
    }
    if (rank < NKEEP) {
      idx[b * NKEEP + rank] = t;
      att_sig[b * NKEEP + rank] = 1.0f / (1.0f + expf(-ai));
      for (int c = 0; c < 4; c++)
        bxk[(b * NKEEP + rank) * 4 + c] = boxes[(b * 4 + c) * NOBJ + t];
    }
  }
  if (t < NKEEP) parent[b * NKEEP + t] = NKEEP;  // sentinel
}

// ---------------------------------------------------------------------------
// K2: gather + split x into A' (fragment-major bf16 [mt][128 ks][g][lane][j]).
// phys ksteps: 0-63 = hi(d), 64-127 = lo(d).
__global__ __launch_bounds__(256) void gather_x(
    const float* __restrict__ vf, const int* __restrict__ idx,
    ushort_t* __restrict__ A2) {
  int b = blockIdx.x;
  int ksh = blockIdx.y;       // = d0/32
  int d0 = ksh * 32;
  __shared__ float s[32][101];
  __shared__ int idxs[NKEEP];
  int tid = threadIdx.x;
  if (tid < NKEEP) idxs[tid] = idx[b * NKEEP + tid];
  for (int l = tid; l < 32 * NOBJ; l += 256) {
    int dd = l / NOBJ, c = l % NOBJ;
    s[dd][c] = vf[((size_t)b * DD + d0 + dd) * NOBJ + c];
  }
  __syncthreads();
  for (int l = tid; l < NKEEP * 32; l += 256) {
    int n = l >> 5, dd = l & 31;
    float v = s[dd][idxs[n]];
    int m = b * NKEEP + n;
    int mt = m >> 7, r = m & 127, g = r >> 4, row16 = r & 15;
    int q = dd >> 3, j = dd & 7;
    int lane = row16 + (q << 4);
    size_t base = ((size_t)mt * 128 + ksh) * 4096 + g * 512 + lane * 8 + j;
    ushort_t hi = f2b(v);
    ushort_t lo = f2b(v - b2f(hi));
    A2[base] = hi;
    A2[base + (size_t)64 * 4096] = lo;
  }
}

// ---------------------------------------------------------------------------
// K3: f[b][n][k] = tanh(sum_d vo[b,d,idx[n]]*Wv[d,k] + sum_c bx*Wb) (f32)
__global__ __launch_bounds__(256) void f_kernel(
    const float* __restrict__ vo, const float* __restrict__ Wv,
    const float* __restrict__ Wb, const int* __restrict__ idx,
    const float* __restrict__ bxk, float* __restrict__ fmat) {
  int b = blockIdx.x;
  int k = threadIdx.x;  // 0..255
  __shared__ int idxs[NKEEP];
  __shared__ float vs[16][NKEEP];
  if (k < NKEEP) idxs[k] = idx[b * NKEEP + k];
  __syncthreads();
  float acc[NKEEP];
#pragma unroll
  for (int n = 0; n < NKEEP; n++) acc[n] = 0.0f;
  for (int d0 = 0; d0 < DD; d0 += 16) {
    __syncthreads();
    for (int l = k; l < 16 * NKEEP; l += 256) {
      int dd = l / NKEEP, n = l % NKEEP;
      vs[dd][n] = vo[((size_t)b * DD + d0 + dd) * NOBJ + idxs[n]];
    }
    __syncthreads();
#pragma unroll
    for (int dd = 0; dd < 16; dd++) {
      float w = Wv[(size_t)(d0 + dd) * KS + k];
#pragma unroll
      for (int n = 0; n < NKEEP; n++) acc[n] += vs[dd][n] * w;
    }
  }
  for (int n = 0; n < NKEEP; n++) {
    float s = acc[n];
#pragma unroll
    for (int c = 0; c < 4; c++) s += bxk[(b * NKEEP + n) * 4 + c] * Wb[c * KS + k];
    fmat[((size_t)b * NKEEP + n) * KS + k] = tanhf(s);
  }
}

// ---------------------------------------------------------------------------
// K4: S[b][i][j] = sigmoid((f_i . f_j)/16) * att_i * att_j   (f64 accum)
__global__ __launch_bounds__(256) void s_kernel(
    const float* __restrict__ fmat, const float* __restrict__ att_sig,
    float* __restrict__ S) {
  int b = blockIdx.x;
  int tid = threadIdx.x;
  __shared__ float fs[NKEEP][KS + 1];
  __shared__ float as[NKEEP];
  for (int l = tid; l < NKEEP * KS; l += 256) {
    int n = l / KS, k = l % KS;
    fs[n][k] = fmat[((size_t)b * NKEEP + n) * KS + k];
  }
  if (tid < NKEEP) as[tid] = att_sig[b * NKEEP + tid];
  __syncthreads();
  for (int p = tid; p < NKEEP * NKEEP; p += 256) {
    int i = p / NKEEP, j = p % NKEEP;
    double acc = 0.0;
    for (int k = 0; k < KS; k++) acc += (double)fs[i][k] * (double)fs[j][k];
    float sc = 1.0f / (1.0f + expf(-(float)(acc * (1.0 / 16.0))));
    S[((size_t)b * NKEEP + i) * NKEEP + j] = sc * as[i] * as[j];
  }
}

// ---------------------------------------------------------------------------
// K5: Prim MST forest, one wave per batch.
__global__ __launch_bounds__(64) void prim_kernel(
    const float* __restrict__ S, int* __restrict__ parent,
    int* __restrict__ order) {
  int b = blockIdx.x;
  int lane = threadIdx.x;
  __shared__ float Ss[NKEEP * NKEEP];
  for (int l = lane; l < NKEEP * NKEEP; l += 64) Ss[l] = S[(size_t)b * NKEEP * NKEEP + l];
  __syncthreads();
  unsigned long long mask = 1ull;  // root = 0 (att sorted desc -> argmax=0)
  if (lane == 0) order[b * NKEEP + 0] = 0;
  for (int step = 1; step < NKEEP; step++) {
    float bv = -1.0f;
    int bk = NKEEP * NKEEP;
    for (int l = lane; l < NKEEP * NKEEP; l += 64) {
      int p = l / NKEEP, c = l % NKEEP;
      if (((mask >> p) & 1ull) && !((mask >> c) & 1ull)) {
        float v = Ss[l];
        if (v > bv || (v == bv && l < bk)) { bv = v; bk = l; }
      }
    }
    for (int off = 32; off > 0; off >>= 1) {
      float ov = __shfl_down(bv, off);
      int ok = __shfl_down(bk, off);
      if (ov > bv || (ov == bv && ok < bk)) { bv = ov; bk = ok; }
    }
    bk = __shfl(bk, 0);
    int p = bk / NKEEP, c = bk % NKEEP;
    mask |= (1ull << c);
    if (lane == 0) {
      parent[b * NKEEP + c] = p;
      order[b * NKEEP + step] = c;
    }
  }
}

// ---------------------------------------------------------------------------
// K6a: build W' fragment-major bf16: [nt:32][ks:128][h:8][lane:64][j:8].
// phys ks 0-63 = W_hi rows, 64-127 = W_lo rows. nt<16 -> Wu, else Wd.
__global__ __launch_bounds__(256) void wconv(
    const float* __restrict__ Wu, const float* __restrict__ Wd,
    ushort_t* __restrict__ B2) {
  int nt = blockIdx.x;   // 0..31
  int ks = blockIdx.y;   // 0..127
  int tid = threadIdx.x;
  const float* W = (nt < 16) ? Wu : Wd;
  int n0 = (nt & 15) * 128;
  int k0 = (ks & 63) * 32;
  bool is_hi = (ks < 64);
  __shared__ float tile[32][129];
  for (int l = tid; l < 32 * 128; l += 256) {
    int kk = l >> 7, c = l & 127;
    tile[kk][c] = W[(size_t)(k0 + kk) * N4H + n0 + c];
  }
  __syncthreads();
  size_t obase = ((size_t)nt * 128 + ks) * 4096 + tid * 16;
#pragma unroll
  for (int u = 0; u < 16; u++) {
    int e = tid * 16 + u;
    int h = e >> 9;
    int lane = (e >> 3) & 63;
    int j = e & 7;
    int c = h * 16 + (lane & 15);
    int kk = (lane >> 4) * 8 + j;
    float v = tile[kk][c];
    ushort_t o;
    if (is_hi) o = f2b(v);
    else { ushort_t hi = f2b(v); o = f2b(v - b2f(hi)); }
    B2[obase + u] = o;
  }
}

// ---------------------------------------------------------------------------
// K6b: pack Wh (f32 [512][2048]) into frag-major bf16 [s:16][f:128][lane:64][j:8]
// value(s,f,l,j) = Wh[32s + (l>>4)*8 + j][16f + (l&15)]
__global__ __launch_bounds__(256) void whpack(
    const float* __restrict__ Wh, ushort_t* __restrict__ Wpk) {
  int s = blockIdx.x;      // 0..15
  int fg = blockIdx.y;     // 0..7
  __shared__ float tile[32][257];
  int tid = threadIdx.x;
  for (int l = tid; l < 32 * 64; l += 256) {
    int row = l >> 6, c4 = (l & 63) * 4;
    float4 v = *(const float4*)&Wh[(size_t)(32 * s + row) * N4H + fg * 256 + c4];
    tile[row][c4] = v.x; tile[row][c4 + 1] = v.y;
    tile[row][c4 + 2] = v.z; tile[row][c4 + 3] = v.w;
  }
  __syncthreads();
#pragma unroll
  for (int it = 0; it < 4; it++) {
    int cid = it * 256 + tid;       // 0..1023
    int ff = cid >> 6, lane = cid & 63;
    int f = fg * 16 + ff;
    int col = ff * 16 + (lane & 15);
    int rbase = (lane >> 4) * 8;
    short8v p;
#pragma unroll
    for (int j = 0; j < 8; j++) p[j] = (short)f2b(tile[rbase + j][col]);
    *(short8v*)&Wpk[(((size_t)s * 128 + f) * 64 + lane) * 8] = p;
  }
}

// ---------------------------------------------------------------------------
// K7: MFMA split-bf16 GEMM, 2-phase double-buffered (T3-min).
// M=9216 (72 mt), N=4096 (32 nt), K'=6144 (192 s).
__global__ __launch_bounds__(256) void mfma_gemm(
    const ushort_t* __restrict__ A2, const ushort_t* __restrict__ B2,
    const float* __restrict__ bu, const float* __restrict__ bd,
    float* __restrict__ Cu, float* __restrict__ Cd) {
  __shared__ __align__(16) ushort_t Asl[2][4096];
  __shared__ __align__(16) ushort_t Bsl[2][4096];
  int bid = blockIdx.x;
  int nt = bid & 31;
  int mt = bid >> 5;
  int tid = threadIdx.x;
  int w = tid >> 6, lane = tid & 63;
  int wr = w >> 1, wc = w & 1;
  f32x4 acc[4][4];
#pragma unroll
  for (int i = 0; i < 4; i++)
#pragma unroll
    for (int j = 0; j < 4; j++) acc[i][j] = (f32x4){0.f, 0.f, 0.f, 0.f};
  const size_t Abase = (size_t)mt * 128 * 4096;
  const size_t Bbase = (size_t)nt * 128 * 4096;

  auto stage = [&](int s, int hb) {
    int aks = (s < 128) ? s : s - 128;
    int bks = (s < 64) ? s : s - 64;
    const ushort_t* ag = A2 + Abase + (size_t)aks * 4096 + (w * 2) * 512 + lane * 8;
    const ushort_t* bg = B2 + Bbase + (size_t)bks * 4096 + (w * 2) * 512 + lane * 8;
    GLOAD_LDS16(ag, &Asl[hb][(w * 2) * 512]);
    GLOAD_LDS16(ag + 512, &Asl[hb][(w * 2 + 1) * 512]);
    GLOAD_LDS16(bg, &Bsl[hb][(w * 2) * 512]);
    GLOAD_LDS16(bg + 512, &Bsl[hb][(w * 2 + 1) * 512]);
  };

  stage(0, 0);
  __syncthreads();
  for (int s = 0; s < 192; ++s) {
    int cur = s & 1;
    if (s < 191) stage(s + 1, cur ^ 1);
    short8v a[4], bfr[4];
#pragma unroll
    for (int mi = 0; mi < 4; mi++)
      a[mi] = *(const short8v*)&Asl[cur][(wr * 4 + mi) * 512 + lane * 8];
#pragma unroll
    for (int ni = 0; ni < 4; ni++)
      bfr[ni] = *(const short8v*)&Bsl[cur][(wc * 4 + ni) * 512 + lane * 8];
#pragma unroll
    for (int mi = 0; mi < 4; mi++)
#pragma unroll
      for (int ni = 0; ni < 4; ni++)
        acc[mi][ni] = __builtin_amdgcn_mfma_f32_16x16x32_bf16(
            a[mi], bfr[ni], acc[mi][ni], 0, 0, 0);
    __syncthreads();  // drains vmcnt (next tile staged) + guards buf reuse
  }
  // epilogue: C/D map col=lane&15, row=(lane>>4)*4+reg  [m89-verified]
  int col16 = lane & 15, rq = lane >> 4;
#pragma unroll
  for (int ni = 0; ni < 4; ni++) {
    int nglob = nt * 128 + wc * 64 + ni * 16 + col16;
    const float* bias = (nt < 16) ? bu : bd;
    float* C = (nt < 16) ? Cu : Cd;
    int nn = (nt < 16) ? nglob : nglob - N4H;
    float bv = bias[nn];
#pragma unroll
    for (int mi = 0; mi < 4; mi++) {
#pragma unroll
      for (int r = 0; r < 4; r++) {
        int m = mt * 128 + wr * 64 + mi * 16 + rq * 4 + r;
        C[(size_t)m * N4H + nn] = acc[mi][ni][r] + bv;
      }
    }
  }
}

// ---------------------------------------------------------------------------
// K8: one fused TreeLSTM step (up + dn in one launch).
// Grid 256 blocks: bid<128 -> up pass (t=35-i), else dn pass (t=i).
// Block = 32 batches (bt) x 32 k-cols (kt) x all 4 gates. 256 thr = 4 waves,
// wave w = gate w. B-frags (Wh packed) straight from L2; A (h state) gathered
// f32 -> bf16 frags in LDS; 16x(2x2) MFMA 16x16x32; fused cell epilogue.
__global__ __launch_bounds__(256) void lstm_step(
    int i,
    const float* __restrict__ xWu, const float* __restrict__ xWd,
    const ushort_t* __restrict__ Wpku, const ushort_t* __restrict__ Wpkd,
    const int* __restrict__ order, const int* __restrict__ parent,
    float* __restrict__ hsum, float* __restrict__ csum,
    float* __restrict__ hup, float* __restrict__ hd, float* __restrict__ cd) {
  int bid = blockIdx.x;
  bool isdn = bid >= 128;
  int lb = isdn ? bid - 128 : bid;
  int bt = lb >> 4, kt = lb & 15;
  int t = isdn ? i : (NKEEP - 1 - i);
  const float* xW = isdn ? xWd : xWu;
  const ushort_t* Wpk = isdn ? Wpkd : Wpku;

  __shared__ __align__(16) ushort_t Apk[16 * 2 * 64 * 8];  // 32 KB
  __shared__ float pre[32][4][36];                          // 18 KB
  __shared__ int nodes[32], pars[32];

  int tid = threadIdx.x;
  if (tid < 32) {
    int b = bt * 32 + tid;
    int nd = order[b * NKEEP + t];
    nodes[tid] = nd;
    pars[tid] = parent[b * NKEEP + nd];
  }
  __syncthreads();
  // ---- A staging: 8 threads per batch, 64B-chunked coalesced reads ----
  {
    int bl = tid >> 3;            // 0..31 local batch
    int r = tid & 7;
    int b = bt * 32 + bl;
    const float* asrc = isdn
        ? &hd[((size_t)b * NP1 + pars[bl]) * H2]
        : &hsum[((size_t)b * NP1 + nodes[bl]) * H2];
    int mf = bl >> 4, l15 = bl & 15;
#pragma unroll
    for (int c = 0; c < 4; c++) {
      int j0 = c * 128 + r * 16;
      float4 v0 = *(const float4*)&asrc[j0];
      float4 v1 = *(const float4*)&asrc[j0 + 4];
      float4 v2 = *(const float4*)&asrc[j0 + 8];
      float4 v3 = *(const float4*)&asrc[j0 + 12];
      int s = j0 >> 5, q = (j0 >> 3) & 3;
      *(short8v*)&Apk[(((s * 2 + mf) * 64) + l15 + q * 16) * 8] = pack8(v0, v1);
      *(short8v*)&Apk[(((s * 2 + mf) * 64) + l15 + (q + 1) * 16) * 8] = pack8(v2, v3);
    }
  }
  __syncthreads();
  // ---- MFMA: wave w = gate; cols = kt*32..+32 of gate w ----
  int w = tid >> 6, lane = tid & 63;
  f32x4 acc[2][2];
#pragma unroll
  for (int mi = 0; mi < 2; mi++)
#pragma unroll
    for (int ci = 0; ci < 2; ci++) acc[mi][ci] = (f32x4){0.f, 0.f, 0.f, 0.f};
  int fbase = w * 32 + kt * 2;
#pragma unroll 4
  for (int s = 0; s < 16; s++) {
    short8v a0 = *(const short8v*)&Apk[((s * 2 + 0) * 64 + lane) * 8];
    short8v a1 = *(const short8v*)&Apk[((s * 2 + 1) * 64 + lane) * 8];
    short8v b0 = *(const short8v*)&Wpk[(((size_t)s * 128 + fbase) * 64 + lane) * 8];
    short8v b1 = *(const short8v*)&Wpk[(((size_t)s * 128 + fbase + 1) * 64 + lane) * 8];
    acc[0][0] = __builtin_amdgcn_mfma_f32_16x16x32_bf16(a0, b0, acc[0][0], 0, 0, 0);
    acc[0][1] = __builtin_amdgcn_mfma_f32_16x16x32_bf16(a0, b1, acc[0][1], 0, 0, 0);
    acc[1][0] = __builtin_amdgcn_mfma_f32_16x16x32_bf16(a1, b0, acc[1][0], 0, 0, 0);
    acc[1][1] = __builtin_amdgcn_mfma_f32_16x16x32_bf16(a1, b1, acc[1][1], 0, 0, 0);
  }
  // scatter pre-activations to LDS: row b_local, gate w, kcol
  int col16 = lane & 15, rq = lane >> 4;
#pragma unroll
  for (int mf = 0; mf < 2; mf++)
#pragma unroll
    for (int cf = 0; cf < 2; cf++)
#pragma unroll
      for (int r = 0; r < 4; r++)
        pre[mf * 16 + rq * 4 + r][w][cf * 16 + col16] = acc[mf][cf][r];
  __syncthreads();
  // ---- cell update: thread -> (bl, 4 consecutive kcols) ----
  {
    int bl = tid >> 3, kc0 = (tid & 7) * 4;
    int b = bt * 32 + bl;
    int nd = nodes[bl], pr = pars[bl];
    int kglob = kt * 32 + kc0;
    const float* xwb = &xW[((size_t)b * NKEEP + nd) * N4H];
    float4 xi = *(const float4*)&xwb[0 * H2 + kglob];
    float4 xf = *(const float4*)&xwb[1 * H2 + kglob];
    float4 xg = *(const float4*)&xwb[2 * H2 + kglob];
    float4 xo = *(const float4*)&xwb[3 * H2 + kglob];
    const float* cpsrc = isdn ? &cd[((size_t)b * NP1 + pr) * H2]
                              : &csum[((size_t)b * NP1 + nd) * H2];
    float4 cp = *(const float4*)&cpsrc[kglob];
    float4 pi4 = *(const float4*)&pre[bl][0][kc0];
    float4 pf4 = *(const float4*)&pre[bl][1][kc0];
    float4 pg4 = *(const float4*)&pre[bl][2][kc0];
    float4 po4 = *(const float4*)&pre[bl][3][kc0];
    float hv[4], cv[4];
    const float* pip = (const float*)&pi4; const float* pfp = (const float*)&pf4;
    const float* pgp = (const float*)&pg4; const float* pop = (const float*)&po4;
    const float* xip = (const float*)&xi;  const float* xfp = (const float*)&xf;
    const float* xgp = (const float*)&xg;  const float* xop = (const float*)&xo;
    const float* cpp = (const float*)&cp;
#pragma unroll
    for (int e = 0; e < 4; e++) {
      float c = sigf(pip[e] + xip[e]) * tanhf(pgp[e] + xgp[e]) +
                sigf(pfp[e] + xfp[e]) * cpp[e];
      hv[e] = sigf(pop[e] + xop[e]) * tanhf(c);
      cv[e] = c;
    }
    float4 h4 = {hv[0], hv[1], hv[2], hv[3]};
    float4 c4 = {cv[0], cv[1], cv[2], cv[3]};
    if (!isdn) {
      *(float4*)&hup[((size_t)b * NKEEP + nd) * H2 + kglob] = h4;
      float* hsp = &hsum[((size_t)b * NP1 + pr) * H2 + kglob];
      float4 hs4 = *(const float4*)hsp;
      hs4.x += h4.x; hs4.y += h4.y; hs4.z += h4.z; hs4.w += h4.w;
      *(float4*)hsp = hs4;
      float* csp = &csum[((size_t)b * NP1 + pr) * H2 + kglob];
      float4 cs4 = *(const float4*)csp;
      cs4.x += c4.x; cs4.y += c4.y; cs4.z += c4.z; cs4.w += c4.w;
      *(float4*)csp = cs4;
    } else {
      *(float4*)&hd[((size_t)b * NP1 + nd) * H2 + kglob] = h4;
      *(float4*)&cd[((size_t)b * NP1 + nd) * H2 + kglob] = c4;
    }
  }
}

// ---------------------------------------------------------------------------
// K9: out[b][q][n] = q<512 ? hup[b][n][q] : hd[b][n][q-512]
__global__ __launch_bounds__(256) void out_transpose(
    const float* __restrict__ hup, const float* __restrict__ hd,
    float* __restrict__ out) {
  int b = blockIdx.x;
  __shared__ float s[NKEEP][65];
  for (int half = 0; half < 2; half++) {
    const float* src = half ? hd : hup;
    int rs = half ? NP1 : NKEEP;
    for (int q0 = 0; q0 < H2; q0 += 64) {
      __syncthreads();
      for (int l = threadIdx.x; l < NKEEP * 64; l += 256) {
        int n = l / 64, qq = l % 64;
        s[n][qq] = src[((size_t)b * rs + n) * H2 + q0 + qq];
      }
      __syncthreads();
      for (int l = threadIdx.x; l < NKEEP * 64; l += 256) {
        int qq = l / NKEEP, n = l % NKEEP;
        out[(size_t)b * (HID * NKEEP) + (half * H2 + q0 + qq) * NKEEP + n] = s[n][qq];
      }
    }
  }
}

// ---------------------------------------------------------------------------
extern "C" void kernel_launch(void* const* d_in, const int* in_sizes, int n_in,
                              void* d_out, int out_size, void* d_ws, size_t ws_size,
                              hipStream_t stream) {
  const float* boxes = (const float*)d_in[0];
  const float* attention = (const float*)d_in[1];
  const float* vf = (const float*)d_in[2];
  const float* vo = (const float*)d_in[3];
  const float* Wv = (const float*)d_in[5];
  const float* Wb = (const float*)d_in[6];
  const float* Wx_up = (const float*)d_in[7];
  const float* Wh_up = (const float*)d_in[8];
  const float* b_up = (const float*)d_in[9];
  const float* Wx_dn = (const float*)d_in[10];
  const float* Wh_dn = (const float*)d_in[11];
  const float* b_dn = (const float*)d_in[12];
  float* out = (float*)d_out;

  char* ws = (char*)d_ws;
  size_t off = 0;
  auto take = [&](size_t bytes) -> char* {
    char* p = ws + off;
    off = (off + bytes + 255) & ~(size_t)255;
    return p;
  };
  int* idx = (int*)take((size_t)BB * NKEEP * 4);
  float* att_sig = (float*)take((size_t)BB * NKEEP * 4);
  float* bxk = (float*)take((size_t)BB * NKEEP * 4 * 4);
  int* parent = (int*)take((size_t)BB * NKEEP * 4);
  int* order = (int*)take((size_t)BB * NKEEP * 4);
  float* fmat = (float*)take((size_t)BB * NKEEP * KS * 4);
  float* S = (float*)take((size_t)BB * NKEEP * NKEEP * 4);
  ushort_t* A2 = (ushort_t*)take((size_t)72 * 128 * 4096 * 2);     // 75.5 MB
  ushort_t* B2 = (ushort_t*)take((size_t)32 * 128 * 4096 * 2);     // 33.6 MB
  float* xWu = (float*)take((size_t)BB * NKEEP * N4H * 4);
  float* xWd = (float*)take((size_t)BB * NKEEP * N4H * 4);
  float* hsum = (float*)take((size_t)BB * NP1 * H2 * 4);
  float* csum = (float*)take((size_t)BB * NP1 * H2 * 4);
  float* hd = (float*)take((size_t)BB * NP1 * H2 * 4);
  float* cd = (float*)take((size_t)BB * NP1 * H2 * 4);
  ushort_t* Wpku = (ushort_t*)take((size_t)16 * 128 * 64 * 8 * 2);  // 2 MB
  ushort_t* Wpkd = (ushort_t*)take((size_t)16 * 128 * 64 * 8 * 2);
  float* hup = (float*)A2;  // alias: A2 dead after mfma_gemm

  topk_kernel<<<BB, 128, 0, stream>>>(attention, boxes, idx, att_sig, bxk, parent);
  gather_x<<<dim3(BB, 64), 256, 0, stream>>>(vf, idx, A2);
  f_kernel<<<BB, 256, 0, stream>>>(vo, Wv, Wb, idx, bxk, fmat);
  s_kernel<<<BB, 256, 0, stream>>>(fmat, att_sig, S);
  prim_kernel<<<BB, 64, 0, stream>>>(S, parent, order);

  wconv<<<dim3(32, 128), 256, 0, stream>>>(Wx_up, Wx_dn, B2);
  whpack<<<dim3(16, 8), 256, 0, stream>>>(Wh_up, Wpku);
  whpack<<<dim3(16, 8), 256, 0, stream>>>(Wh_dn, Wpkd);

  mfma_gemm<<<72 * 32, 256, 0, stream>>>(A2, B2, b_up, b_dn, xWu, xWd);

  size_t accb = (size_t)BB * NP1 * H2 * 4;
  hipMemsetAsync(hsum, 0, accb * 4, stream);  // hsum,csum,hd,cd contiguous

  for (int i = 0; i < NKEEP; ++i)
    lstm_step<<<256, 256, 0, stream>>>(i, xWu, xWd, Wpku, Wpkd, order, parent,
                                       hsum, csum, hup, hd, cd);

  out_transpose<<<BB, 256, 0, stream>>>(hup, hd, out);
}